// Round 2
// baseline (546.200 us; speedup 1.0000x reference)
//
#include <hip/hip_runtime.h>
#include <hip/hip_bf16.h>
#include <math.h>

// ---- problem constants ----
#define NB 256      // batch
#define NN 307      // vertices
#define NBN 78592   // NB*NN
#define LL 12       // sequence length
#define DDIM 16     // model dim
#define HISW 268    // 267 history cols + 1 zero pad (for float4)
#define HIS4 67     // HISW/4
#define NBRCAP 128  // per-row neighbor capacity
#define GPB 5       // bn pairs per wave in attn

// ---- workspace layout (float offsets; every segment 16B-aligned) ----
#define OFF_XTCN 0u            // 15089664 floats  [B,N,L,D]
#define OFF_G1   15089664u     //   943104 floats  [B,N,L]
#define OFF_ADT  16032768u     //    94249 floats  A_dyn^T [m][n] (pad to 94256)
#define OFF_TE   16127024u     //    49152 floats  [B,L,D] = pe + day_emb + week_emb
#define OFF_HIS  16176176u     //    82276 floats  [N,268] (pad to 82288)
#define OFF_NW   16258464u     //    39296 floats  nbr weights [N,128]
#define OFF_NIDX 16297760u     //    39296 ints    nbr indices [N,128]
#define OFF_NCNT 16337056u     //      307 ints    nbr counts

__device__ inline float4 mkf4(float a, float b, float c, float d) {
    float4 r; r.x = a; r.y = b; r.z = c; r.w = d; return r;
}

// ---------------------------------------------------------------------------
// K0a: build padded history matrix his[N][268]
// ---------------------------------------------------------------------------
__global__ void his_kernel(const float* __restrict__ flow, float* __restrict__ his) {
    int e = blockIdx.x * 256 + threadIdx.x;
    if (e >= NN * HISW) return;
    int n = e / HISW, j = e - n * HISW;
    float v = 0.f;
    if (j < LL) v = flow[n * LL + j];
    else if (j < 267) v = flow[((j - 11) * NN + n) * LL + 11];
    his[e] = v;
}

// ---------------------------------------------------------------------------
// K0b: TE[b,l,d] = pos_enc + day_emb[day_cyc] + week_emb[week_cyc]
// ---------------------------------------------------------------------------
__global__ void te_kernel(const int* __restrict__ dayc, const int* __restrict__ weekc,
                          const float* __restrict__ demb, const float* __restrict__ wemb,
                          float* __restrict__ TE) {
    int e = blockIdx.x * 256 + threadIdx.x;
    if (e >= NB * LL * DDIM) return;
    int d = e & 15, l = (e >> 4) % LL, b = e / (LL * DDIM);
    int dc = dayc[b * LL + l], wc = weekc[b * LL + l];
    int i = d >> 1;
    float ang = (float)l * powf(10000.f, -0.125f * (float)i);
    float pe = (d & 1) ? cosf(ang) : sinf(ang);
    TE[e] = demb[dc * DDIM + d] + wemb[wc * DDIM + d] + pe;
}

// ---------------------------------------------------------------------------
// K1: A_dyn row-softmax of -dist, stored transposed AdT[m*307+n]
// ---------------------------------------------------------------------------
__global__ __launch_bounds__(256) void adyn_kernel(const float* __restrict__ his,
                                                   float* __restrict__ AdT) {
    __shared__ float4 sh[HIS4];
    __shared__ float red[256];
    int n = blockIdx.x, t = threadIdx.x;
    if (t < HIS4) sh[t] = reinterpret_cast<const float4*>(his)[n * HIS4 + t];
    __syncthreads();

    float e0 = 0.f, e1 = 0.f, lsum = 0.f;
    {
        const float4* row = reinterpret_cast<const float4*>(his) + t * HIS4;
        float4 acc = mkf4(0.f, 0.f, 0.f, 0.f);
        for (int j = 0; j < HIS4; j++) {
            float4 a = sh[j], b = row[j];
            float dx = a.x - b.x, dy = a.y - b.y, dz = a.z - b.z, dw = a.w - b.w;
            acc.x += dx * dx; acc.y += dy * dy; acc.z += dz * dz; acc.w += dw * dw;
        }
        float d2 = (acc.x + acc.y) + (acc.z + acc.w);
        e0 = __expf(-sqrtf(fmaxf(d2, 0.f)));
        lsum += e0;
    }
    int m1 = t + 256;
    if (m1 < NN) {
        const float4* row = reinterpret_cast<const float4*>(his) + m1 * HIS4;
        float4 acc = mkf4(0.f, 0.f, 0.f, 0.f);
        for (int j = 0; j < HIS4; j++) {
            float4 a = sh[j], b = row[j];
            float dx = a.x - b.x, dy = a.y - b.y, dz = a.z - b.z, dw = a.w - b.w;
            acc.x += dx * dx; acc.y += dy * dy; acc.z += dz * dz; acc.w += dw * dw;
        }
        float d2 = (acc.x + acc.y) + (acc.z + acc.w);
        e1 = __expf(-sqrtf(fmaxf(d2, 0.f)));
        lsum += e1;
    }
    red[t] = lsum;
    __syncthreads();
    for (int s = 128; s > 0; s >>= 1) {
        if (t < s) red[t] += red[t + s];
        __syncthreads();
    }
    float inv = 1.f / red[0];
    AdT[t * NN + n] = e0 * inv;
    if (m1 < NN) AdT[m1 * NN + n] = e1 * inv;
}

// ---------------------------------------------------------------------------
// K2: sparse A_st rows (ballot compaction)
// ---------------------------------------------------------------------------
__global__ __launch_bounds__(64) void nbr_kernel(const float* __restrict__ adj,
                                                 int* __restrict__ ncnt,
                                                 int* __restrict__ nidx,
                                                 float* __restrict__ nw) {
    int n = blockIdx.x, t = threadIdx.x;
    float rs = 0.f;
    for (int m0 = 0; m0 < NN; m0 += 64) {
        int m = m0 + t;
        if (m < NN) rs += adj[n * NN + m];
    }
    for (int off = 32; off > 0; off >>= 1) rs += __shfl_xor(rs, off);
    float inv = 1.f / (rs + 1.f);
    int c = 0;
    for (int m0 = 0; m0 < NN; m0 += 64) {
        int m = m0 + t;
        float a = (m < NN) ? adj[n * NN + m] : 0.f;
        bool p = (a != 0.f);
        unsigned long long mask = __ballot(p);
        int pos = __popcll(mask & ((1ull << t) - 1ull));
        if (p && (c + pos) < NBRCAP) {
            nidx[n * NBRCAP + c + pos] = m;
            nw[n * NBRCAP + c + pos] = a * inv;
        }
        c += (int)__popcll(mask);
    }
    if (t == 0) ncnt[n] = c < NBRCAP ? c : NBRCAP;
}

// ---------------------------------------------------------------------------
// K3 v2: temporal self-attention, 5 bn per 64-lane wave.
// Stage A (60 lanes = 5bn x 12 rows): x row in regs, q/k/v via scalar-W FMAs,
//   k,v,q -> LDS (row stride 20 floats for bank spread).
// Stage B (40 lanes = 5bn x 8 heads): softmax(QK^T/sqrt2)@V from LDS,
//   att written back over sK (dead after B; program order makes alias safe).
// Stage C (60 lanes, same mapping as A): out = x + att@Wo + bo -> global.
// Single-wave block: __syncthreads() degenerates to waitcnt.
// ---------------------------------------------------------------------------
__global__ __launch_bounds__(64) void attn_kernel(
    const float* __restrict__ flow, const float* __restrict__ TE,
    const float* __restrict__ Wq, const float* __restrict__ bq,
    const float* __restrict__ Wk, const float* __restrict__ bk,
    const float* __restrict__ Wv, const float* __restrict__ bv,
    const float* __restrict__ Wo, const float* __restrict__ bo,
    float* __restrict__ xtcn) {
    __shared__ float sK[GPB][LL][20];
    __shared__ float sV[GPB][LL][20];
    __shared__ float sQ[GPB][LL][20];
    float* sA = &sK[0][0][0];  // alias: att overwrites K after it is consumed

    const int t = threadIdx.x;
    const int bn0 = blockIdx.x * GPB;
    const int g = t / LL, l = t - g * LL;   // row mapping (valid t<60)
    const int bn = bn0 + g;
    const bool rowAct = (t < 60) && (bn < NBN);

    float x[16];
    if (rowAct) {
        const int b = bn / NN;
        float f = flow[bn * LL + l];
        const float4* te4 = reinterpret_cast<const float4*>(TE + (b * LL + l) * DDIM);
        float4 t0 = te4[0], t1 = te4[1], t2 = te4[2], t3 = te4[3];
        x[0] = f + t0.x; x[1] = f + t0.y; x[2] = f + t0.z; x[3] = f + t0.w;
        x[4] = f + t1.x; x[5] = f + t1.y; x[6] = f + t1.z; x[7] = f + t1.w;
        x[8] = f + t2.x; x[9] = f + t2.y; x[10] = f + t2.z; x[11] = f + t2.w;
        x[12] = f + t3.x; x[13] = f + t3.y; x[14] = f + t3.z; x[15] = f + t3.w;

        float q[16], k[16], v[16];
#pragma unroll
        for (int d = 0; d < 16; d++) { q[d] = bq[d]; k[d] = bk[d]; v[d] = bv[d]; }
#pragma unroll
        for (int e = 0; e < 16; e++) {
            float xe = x[e];
#pragma unroll
            for (int d = 0; d < 16; d++) {
                q[d] += xe * Wq[e * 16 + d];   // W operands uniform -> s_load
                k[d] += xe * Wk[e * 16 + d];
                v[d] += xe * Wv[e * 16 + d];
            }
        }
        float4* kd = reinterpret_cast<float4*>(&sK[g][l][0]);
        float4* vd = reinterpret_cast<float4*>(&sV[g][l][0]);
        float4* qd = reinterpret_cast<float4*>(&sQ[g][l][0]);
#pragma unroll
        for (int j = 0; j < 4; j++) {
            kd[j] = mkf4(k[4 * j], k[4 * j + 1], k[4 * j + 2], k[4 * j + 3]);
            vd[j] = mkf4(v[4 * j], v[4 * j + 1], v[4 * j + 2], v[4 * j + 3]);
            qd[j] = mkf4(q[4 * j], q[4 * j + 1], q[4 * j + 2], q[4 * j + 3]);
        }
    }
    __syncthreads();

    if (t < 40) {
        int gg = t >> 3, h = t & 7;
        if (bn0 + gg < NBN) {
            float2 kk[LL], vv[LL];
#pragma unroll
            for (int m = 0; m < LL; m++) {
                kk[m] = *reinterpret_cast<const float2*>(&sK[gg][m][2 * h]);
                vv[m] = *reinterpret_cast<const float2*>(&sV[gg][m][2 * h]);
            }
            float2 att[LL];
#pragma unroll
            for (int l2 = 0; l2 < LL; l2++) {
                float2 q2 = *reinterpret_cast<const float2*>(&sQ[gg][l2][2 * h]);
                float s[LL];
                float sum = 0.f;
#pragma unroll
                for (int m = 0; m < LL; m++) {
                    s[m] = __expf((q2.x * kk[m].x + q2.y * kk[m].y) * 0.70710678118654752f);
                    sum += s[m];
                }
                float a0 = 0.f, a1 = 0.f;
#pragma unroll
                for (int m = 0; m < LL; m++) { a0 += s[m] * vv[m].x; a1 += s[m] * vv[m].y; }
                float inv = 1.f / sum;
                att[l2].x = a0 * inv; att[l2].y = a1 * inv;
            }
#pragma unroll
            for (int l2 = 0; l2 < LL; l2++) {
                *reinterpret_cast<float2*>(&sA[(gg * LL + l2) * 20 + 2 * h]) = att[l2];
            }
        }
    }
    __syncthreads();

    if (rowAct) {
        float a[16];
        const float4* ar = reinterpret_cast<const float4*>(&sA[(g * LL + l) * 20]);
        float4 a0 = ar[0], a1 = ar[1], a2 = ar[2], a3 = ar[3];
        a[0] = a0.x; a[1] = a0.y; a[2] = a0.z; a[3] = a0.w;
        a[4] = a1.x; a[5] = a1.y; a[6] = a1.z; a[7] = a1.w;
        a[8] = a2.x; a[9] = a2.y; a[10] = a2.z; a[11] = a2.w;
        a[12] = a3.x; a[13] = a3.y; a[14] = a3.z; a[15] = a3.w;
        float o[16];
#pragma unroll
        for (int d = 0; d < 16; d++) o[d] = bo[d];
#pragma unroll
        for (int e = 0; e < 16; e++) {
            float ae = a[e];
#pragma unroll
            for (int d = 0; d < 16; d++) o[d] += ae * Wo[e * 16 + d];  // scalar W
        }
        float4* dst = reinterpret_cast<float4*>(xtcn) + (size_t)bn * 48 + l * 4;
#pragma unroll
        for (int j = 0; j < 4; j++) {
            dst[j] = mkf4(x[4 * j] + o[4 * j], x[4 * j + 1] + o[4 * j + 1],
                          x[4 * j + 2] + o[4 * j + 2], x[4 * j + 3] + o[4 * j + 3]);
        }
    }
}

// ---------------------------------------------------------------------------
// K4 v2: G1[b,n,l] = sum_m AdT[m][n] * flow[b,m,l], m-reduction split 4-way
// (grid 256x4 = 20 waves/CU instead of 5). G1 zeroed by memset; atomicAdd.
// ---------------------------------------------------------------------------
__global__ __launch_bounds__(320) void g1_kernel(const float* __restrict__ flow,
                                                 const float* __restrict__ AdT,
                                                 float* __restrict__ G1) {
    int b = blockIdx.x, c = blockIdx.y, n = threadIdx.x;
    if (n >= NN) return;
    int m0 = c * 77, m1 = m0 + 77 < NN ? m0 + 77 : NN;
    const float* fb = flow + (size_t)b * NN * LL;
    float acc[LL];
#pragma unroll
    for (int l = 0; l < LL; l++) acc[l] = 0.f;
    for (int m = m0; m < m1; m++) {
        float w = AdT[m * NN + n];
        float fr[LL];
#pragma unroll
        for (int l = 0; l < LL; l++) fr[l] = fb[m * LL + l];   // uniform -> scalar
#pragma unroll
        for (int l = 0; l < LL; l++) acc[l] += w * fr[l];
    }
    float* dst = G1 + ((size_t)b * NN + n) * LL;
#pragma unroll
    for (int l = 0; l < LL; l++) atomicAdd(&dst[l], acc[l]);
}

// ---------------------------------------------------------------------------
// K5: fused graph-mix + MLP head (gather loop unrolled x2 for load ILP)
// ---------------------------------------------------------------------------
__global__ __launch_bounds__(64) void final_kernel(
    const float* __restrict__ xtcn, const float* __restrict__ G1,
    const float* __restrict__ Wg, const float* __restrict__ Wt,
    const float* __restrict__ bg, const float* __restrict__ W1,
    const float* __restrict__ b1, const float* __restrict__ W2,
    const float* __restrict__ b2, const int* __restrict__ ncnt,
    const int* __restrict__ nidx, const float* __restrict__ nw,
    float* __restrict__ out) {
    __shared__ float sY[192];
    __shared__ float4 sHID[96];
    __shared__ float sH1[96];
    int t = threadIdx.x, bn = blockIdx.x;
    int b = bn / NN, n = bn - b * NN;

    int cnt = ncnt[n];
    float y0 = 0.f, y1 = 0.f, y2 = 0.f;
    const float* base = xtcn + (size_t)b * NN * 192;
    int i = 0;
    for (; i + 1 < cnt; i += 2) {
        int ma = nidx[n * NBRCAP + i], mb = nidx[n * NBRCAP + i + 1];
        float wa = nw[n * NBRCAP + i], wb = nw[n * NBRCAP + i + 1];
        const float* sa = base + ma * 192;
        const float* sb = base + mb * 192;
        float a0 = sa[t], a1 = sa[t + 64], a2 = sa[t + 128];
        float c0 = sb[t], c1 = sb[t + 64], c2 = sb[t + 128];
        y0 += wa * a0 + wb * c0; y1 += wa * a1 + wb * c1; y2 += wa * a2 + wb * c2;
    }
    if (i < cnt) {
        int ma = nidx[n * NBRCAP + i];
        float wa = nw[n * NBRCAP + i];
        const float* sa = base + ma * 192;
        y0 += wa * sa[t]; y1 += wa * sa[t + 64]; y2 += wa * sa[t + 128];
    }
    sY[t] = y0; sY[t + 64] = y1; sY[t + 128] = y2;
    __syncthreads();

#pragma unroll
    for (int p = 0; p < 2; p++) {
        int c = t + p * 64;
        if (c < 96) {
            int l = c >> 3, j = c & 7;
            float g = G1[(size_t)bn * LL + l];
            float4 wg = reinterpret_cast<const float4*>(Wg)[j];
            float4 acc = reinterpret_cast<const float4*>(bg)[j];
            acc.x += g * wg.x; acc.y += g * wg.y; acc.z += g * wg.z; acc.w += g * wg.w;
            const float4* yr = reinterpret_cast<const float4*>(sY) + l * 4;
            float4 v0 = yr[0], v1 = yr[1], v2 = yr[2], v3 = yr[3];
            float ye[16] = {v0.x, v0.y, v0.z, v0.w, v1.x, v1.y, v1.z, v1.w,
                            v2.x, v2.y, v2.z, v2.w, v3.x, v3.y, v3.z, v3.w};
#pragma unroll
            for (int d = 0; d < 16; d++) {
                float4 wt = reinterpret_cast<const float4*>(Wt)[d * 8 + j];
                acc.x += ye[d] * wt.x; acc.y += ye[d] * wt.y;
                acc.z += ye[d] * wt.z; acc.w += ye[d] * wt.w;
            }
            acc.x = fmaxf(acc.x, 0.f); acc.y = fmaxf(acc.y, 0.f);
            acc.z = fmaxf(acc.z, 0.f); acc.w = fmaxf(acc.w, 0.f);
            sHID[c] = acc;
        }
    }
    __syncthreads();

#pragma unroll
    for (int p = 0; p < 2; p++) {
        int o = t + p * 64;
        if (o < 96) {
            int l = o >> 3, oo = o & 7;
            float acc = b1[n * 8 + oo];
            float he[32];
#pragma unroll
            for (int k = 0; k < 8; k++) {
                float4 hv = sHID[l * 8 + k];
                he[4 * k + 0] = hv.x; he[4 * k + 1] = hv.y;
                he[4 * k + 2] = hv.z; he[4 * k + 3] = hv.w;
            }
#pragma unroll
            for (int c = 0; c < 32; c++) acc += he[c] * W1[(n * 32 + c) * 8 + oo];
            sH1[o] = fmaxf(acc, 0.f);
        }
    }
    __syncthreads();

    if (t < LL) {
        float acc = b2[n];
#pragma unroll
        for (int o = 0; o < 8; o++) acc += sH1[t * 8 + o] * W2[n * 8 + o];
        out[(size_t)bn * LL + t] = acc;
    }
}

// ---------------------------------------------------------------------------
extern "C" void kernel_launch(void* const* d_in, const int* in_sizes, int n_in,
                              void* d_out, int out_size, void* d_ws, size_t ws_size,
                              hipStream_t stream) {
    const float* flow = (const float*)d_in[0];
    const int* dayc   = (const int*)d_in[1];
    const int* weekc  = (const int*)d_in[2];
    const float* adj  = (const float*)d_in[3];
    const float* demb = (const float*)d_in[4];
    const float* wemb = (const float*)d_in[5];
    const float* Wq = (const float*)d_in[6];  const float* bq = (const float*)d_in[7];
    const float* Wk = (const float*)d_in[8];  const float* bk = (const float*)d_in[9];
    const float* Wv = (const float*)d_in[10]; const float* bv = (const float*)d_in[11];
    const float* Wo = (const float*)d_in[12]; const float* bo = (const float*)d_in[13];
    const float* Wg = (const float*)d_in[14]; const float* Wt = (const float*)d_in[15];
    const float* bg = (const float*)d_in[16];
    const float* W1 = (const float*)d_in[17]; const float* b1 = (const float*)d_in[18];
    const float* W2 = (const float*)d_in[19]; const float* b2 = (const float*)d_in[20];
    float* out = (float*)d_out;
    float* ws  = (float*)d_ws;

    float* xtcn = ws + OFF_XTCN;
    float* G1   = ws + OFF_G1;
    float* AdT  = ws + OFF_ADT;
    float* TE   = ws + OFF_TE;
    float* his  = ws + OFF_HIS;
    float* nw   = ws + OFF_NW;
    int*   nidx = (int*)(ws + OFF_NIDX);
    int*   ncnt = (int*)(ws + OFF_NCNT);

    hipMemsetAsync(G1, 0, (size_t)NB * NN * LL * sizeof(float), stream);
    his_kernel<<<(NN * HISW + 255) / 256, 256, 0, stream>>>(flow, his);
    te_kernel<<<(NB * LL * DDIM + 255) / 256, 256, 0, stream>>>(dayc, weekc, demb, wemb, TE);
    adyn_kernel<<<NN, 256, 0, stream>>>(his, AdT);
    nbr_kernel<<<NN, 64, 0, stream>>>(adj, ncnt, nidx, nw);
    attn_kernel<<<(NBN + GPB - 1) / GPB, 64, 0, stream>>>(flow, TE, Wq, bq, Wk, bk,
                                                          Wv, bv, Wo, bo, xtcn);
    g1_kernel<<<dim3(NB, 4), 320, 0, stream>>>(flow, AdT, G1);
    final_kernel<<<NBN, 64, 0, stream>>>(xtcn, G1, Wg, Wt, bg, W1, b1, W2, b2,
                                         ncnt, nidx, nw, out);
}

// Round 3
// 326.652 us; speedup vs baseline: 1.6721x; 1.6721x over previous
//
#include <hip/hip_runtime.h>
#include <hip/hip_bf16.h>
#include <math.h>

// ---- problem constants ----
#define NB 256      // batch
#define NN 307      // vertices
#define NBN 78592   // NB*NN
#define LL 12       // sequence length
#define DDIM 16     // model dim
#define HISW 268    // 267 history cols + 1 zero pad (for float4)
#define HIS4 67     // HISW/4
#define NBRCAP 128  // per-row neighbor capacity
#define AGRP 21     // bn rows per 256-thread block in attn (252 lanes active)
#define ADTS 308    // AdT row stride (padded even for float2 alignment)

// ---- workspace layout (float offsets; every segment 16B-aligned) ----
#define OFF_XTCN 0u            // 15089664 floats  [B,N,L,D]
#define OFF_G1   15089664u     //   943104 floats  [B,N,L]
#define OFF_ADT  16032768u     //    94688 floats  A_dyn^T [m][308]
#define OFF_TE   16127456u     //    49152 floats  [B,L,D]
#define OFF_HIS  16176608u     //    82288 floats  [N,268]
#define OFF_NW   16258896u     //    39296 floats  nbr weights [N,128]
#define OFF_NIDX 16298192u     //    39296 ints    nbr indices [N,128]
#define OFF_NCNT 16337488u     //      320 ints    nbr counts

__device__ inline float4 mkf4(float a, float b, float c, float d) {
    float4 r; r.x = a; r.y = b; r.z = c; r.w = d; return r;
}

// ---------------------------------------------------------------------------
// K0a: build padded history matrix his[N][268]
// ---------------------------------------------------------------------------
__global__ void his_kernel(const float* __restrict__ flow, float* __restrict__ his) {
    int e = blockIdx.x * 256 + threadIdx.x;
    if (e >= NN * HISW) return;
    int n = e / HISW, j = e - n * HISW;
    float v = 0.f;
    if (j < LL) v = flow[n * LL + j];
    else if (j < 267) v = flow[((j - 11) * NN + n) * LL + 11];
    his[e] = v;
}

// ---------------------------------------------------------------------------
// K0b: TE[b,l,d] = pos_enc + day_emb[day_cyc] + week_emb[week_cyc]
// ---------------------------------------------------------------------------
__global__ void te_kernel(const int* __restrict__ dayc, const int* __restrict__ weekc,
                          const float* __restrict__ demb, const float* __restrict__ wemb,
                          float* __restrict__ TE) {
    int e = blockIdx.x * 256 + threadIdx.x;
    if (e >= NB * LL * DDIM) return;
    int d = e & 15, l = (e >> 4) % LL, b = e / (LL * DDIM);
    int dc = dayc[b * LL + l], wc = weekc[b * LL + l];
    int i = d >> 1;
    float ang = (float)l * powf(10000.f, -0.125f * (float)i);
    float pe = (d & 1) ? cosf(ang) : sinf(ang);
    TE[e] = demb[dc * DDIM + d] + wemb[wc * DDIM + d] + pe;
}

// ---------------------------------------------------------------------------
// K1: A_dyn row-softmax of -dist, stored transposed AdT[m*308+n]
// ---------------------------------------------------------------------------
__global__ __launch_bounds__(256) void adyn_kernel(const float* __restrict__ his,
                                                   float* __restrict__ AdT) {
    __shared__ float4 sh[HIS4];
    __shared__ float red[256];
    int n = blockIdx.x, t = threadIdx.x;
    if (t < HIS4) sh[t] = reinterpret_cast<const float4*>(his)[n * HIS4 + t];
    __syncthreads();

    float e0 = 0.f, e1 = 0.f, lsum = 0.f;
    {
        const float4* row = reinterpret_cast<const float4*>(his) + t * HIS4;
        float4 acc = mkf4(0.f, 0.f, 0.f, 0.f);
        for (int j = 0; j < HIS4; j++) {
            float4 a = sh[j], b = row[j];
            float dx = a.x - b.x, dy = a.y - b.y, dz = a.z - b.z, dw = a.w - b.w;
            acc.x += dx * dx; acc.y += dy * dy; acc.z += dz * dz; acc.w += dw * dw;
        }
        float d2 = (acc.x + acc.y) + (acc.z + acc.w);
        e0 = __expf(-sqrtf(fmaxf(d2, 0.f)));
        lsum += e0;
    }
    int m1 = t + 256;
    if (m1 < NN) {
        const float4* row = reinterpret_cast<const float4*>(his) + m1 * HIS4;
        float4 acc = mkf4(0.f, 0.f, 0.f, 0.f);
        for (int j = 0; j < HIS4; j++) {
            float4 a = sh[j], b = row[j];
            float dx = a.x - b.x, dy = a.y - b.y, dz = a.z - b.z, dw = a.w - b.w;
            acc.x += dx * dx; acc.y += dy * dy; acc.z += dz * dz; acc.w += dw * dw;
        }
        float d2 = (acc.x + acc.y) + (acc.z + acc.w);
        e1 = __expf(-sqrtf(fmaxf(d2, 0.f)));
        lsum += e1;
    }
    red[t] = lsum;
    __syncthreads();
    for (int s = 128; s > 0; s >>= 1) {
        if (t < s) red[t] += red[t + s];
        __syncthreads();
    }
    float inv = 1.f / red[0];
    AdT[t * ADTS + n] = e0 * inv;
    if (m1 < NN) AdT[m1 * ADTS + n] = e1 * inv;
}

// ---------------------------------------------------------------------------
// K2: sparse A_st rows (ballot compaction)
// ---------------------------------------------------------------------------
__global__ __launch_bounds__(64) void nbr_kernel(const float* __restrict__ adj,
                                                 int* __restrict__ ncnt,
                                                 int* __restrict__ nidx,
                                                 float* __restrict__ nw) {
    int n = blockIdx.x, t = threadIdx.x;
    float rs = 0.f;
    for (int m0 = 0; m0 < NN; m0 += 64) {
        int m = m0 + t;
        if (m < NN) rs += adj[n * NN + m];
    }
    for (int off = 32; off > 0; off >>= 1) rs += __shfl_xor(rs, off);
    float inv = 1.f / (rs + 1.f);
    int c = 0;
    for (int m0 = 0; m0 < NN; m0 += 64) {
        int m = m0 + t;
        float a = (m < NN) ? adj[n * NN + m] : 0.f;
        bool p = (a != 0.f);
        unsigned long long mask = __ballot(p);
        int pos = __popcll(mask & ((1ull << t) - 1ull));
        if (p && (c + pos) < NBRCAP) {
            nidx[n * NBRCAP + c + pos] = m;
            nw[n * NBRCAP + c + pos] = a * inv;
        }
        c += (int)__popcll(mask);
    }
    if (t == 0) ncnt[n] = c < NBRCAP ? c : NBRCAP;
}

// ---------------------------------------------------------------------------
// K3 v3: temporal self-attention. 256 threads = 21 bn rows-groups of 12.
// W matrices staged to LDS once (broadcast reads, no global W traffic).
// Lane (g,l): computes its x row, q/k/v (q stays in regs), writes k,v to LDS;
// after one barrier the SAME lane does all 8 heads softmax+PV for its row
// (att in regs), then the out-projection + residual + store. 252/256 lanes
// active in every stage; 2 barriers total.
// ---------------------------------------------------------------------------
__global__ __launch_bounds__(256) void attn_kernel(
    const float* __restrict__ flow, const float* __restrict__ TE,
    const float* __restrict__ Wq, const float* __restrict__ bq,
    const float* __restrict__ Wk, const float* __restrict__ bk,
    const float* __restrict__ Wv, const float* __restrict__ bv,
    const float* __restrict__ Wo, const float* __restrict__ bo,
    float* __restrict__ xtcn) {
    __shared__ __align__(16) float sW[4][256];
    __shared__ __align__(16) float sBias[4][16];
    __shared__ __align__(16) float sKV[2][AGRP][LL][20];

    const int t = threadIdx.x;
    // stage weights (1024 floats) + biases (64)
    for (int id = t; id < 1024; id += 256) {
        int mat = id >> 8, idx = id & 255;
        float v = (mat == 0) ? Wq[idx] : (mat == 1) ? Wk[idx] : (mat == 2) ? Wv[idx] : Wo[idx];
        sW[mat][idx] = v;
    }
    if (t < 64) {
        int mat = t >> 4, d = t & 15;
        sBias[mat][d] = (mat == 0) ? bq[d] : (mat == 1) ? bk[d] : (mat == 2) ? bv[d] : bo[d];
    }

    const int g = t / LL, l = t - g * LL;
    const int bn = blockIdx.x * AGRP + g;
    const bool act = (t < AGRP * LL) && (bn < NBN);

    float x[16];
    if (act) {
        const int b = bn / NN;
        float f = flow[bn * LL + l];
        const float4* te4 = reinterpret_cast<const float4*>(TE + (b * LL + l) * DDIM);
        float4 t0 = te4[0], t1 = te4[1], t2 = te4[2], t3 = te4[3];
        x[0] = f + t0.x; x[1] = f + t0.y; x[2] = f + t0.z; x[3] = f + t0.w;
        x[4] = f + t1.x; x[5] = f + t1.y; x[6] = f + t1.z; x[7] = f + t1.w;
        x[8] = f + t2.x; x[9] = f + t2.y; x[10] = f + t2.z; x[11] = f + t2.w;
        x[12] = f + t3.x; x[13] = f + t3.y; x[14] = f + t3.z; x[15] = f + t3.w;
    }
    __syncthreads();   // sW/sBias ready

    float q[16];
    if (act) {
        float k[16], v[16];
#pragma unroll
        for (int d = 0; d < 16; d++) {
            q[d] = sBias[0][d]; k[d] = sBias[1][d]; v[d] = sBias[2][d];
        }
#pragma unroll
        for (int e = 0; e < 16; e++) {
            float xe = x[e];
            const float4* wq = reinterpret_cast<const float4*>(&sW[0][e * 16]);
            const float4* wk = reinterpret_cast<const float4*>(&sW[1][e * 16]);
            const float4* wv = reinterpret_cast<const float4*>(&sW[2][e * 16]);
#pragma unroll
            for (int j = 0; j < 4; j++) {
                float4 a = wq[j];
                q[4 * j] += xe * a.x; q[4 * j + 1] += xe * a.y;
                q[4 * j + 2] += xe * a.z; q[4 * j + 3] += xe * a.w;
                float4 bb = wk[j];
                k[4 * j] += xe * bb.x; k[4 * j + 1] += xe * bb.y;
                k[4 * j + 2] += xe * bb.z; k[4 * j + 3] += xe * bb.w;
                float4 c = wv[j];
                v[4 * j] += xe * c.x; v[4 * j + 1] += xe * c.y;
                v[4 * j + 2] += xe * c.z; v[4 * j + 3] += xe * c.w;
            }
        }
        float4* kd = reinterpret_cast<float4*>(&sKV[0][g][l][0]);
        float4* vd = reinterpret_cast<float4*>(&sKV[1][g][l][0]);
#pragma unroll
        for (int j = 0; j < 4; j++) {
            kd[j] = mkf4(k[4 * j], k[4 * j + 1], k[4 * j + 2], k[4 * j + 3]);
            vd[j] = mkf4(v[4 * j], v[4 * j + 1], v[4 * j + 2], v[4 * j + 3]);
        }
    }
    __syncthreads();   // k,v visible

    if (act) {
        float att[16];
#pragma unroll
        for (int h = 0; h < 8; h++) {
            float qx = q[2 * h], qy = q[2 * h + 1];
            float s[LL];
            float sum = 0.f;
#pragma unroll
            for (int m = 0; m < LL; m++) {
                float2 kk = *reinterpret_cast<const float2*>(&sKV[0][g][m][2 * h]);
                s[m] = __expf((qx * kk.x + qy * kk.y) * 0.70710678118654752f);
                sum += s[m];
            }
            float a0 = 0.f, a1 = 0.f;
#pragma unroll
            for (int m = 0; m < LL; m++) {
                float2 vv = *reinterpret_cast<const float2*>(&sKV[1][g][m][2 * h]);
                a0 += s[m] * vv.x; a1 += s[m] * vv.y;
            }
            float inv = 1.f / sum;
            att[2 * h] = a0 * inv; att[2 * h + 1] = a1 * inv;
        }
        // out-projection + residual
        float o[16];
#pragma unroll
        for (int d = 0; d < 16; d++) o[d] = sBias[3][d];
#pragma unroll
        for (int e = 0; e < 16; e++) {
            float ae = att[e];
            const float4* wo = reinterpret_cast<const float4*>(&sW[3][e * 16]);
#pragma unroll
            for (int j = 0; j < 4; j++) {
                float4 w = wo[j];
                o[4 * j] += ae * w.x; o[4 * j + 1] += ae * w.y;
                o[4 * j + 2] += ae * w.z; o[4 * j + 3] += ae * w.w;
            }
        }
        float4* dst = reinterpret_cast<float4*>(xtcn) + (size_t)bn * 48 + l * 4;
#pragma unroll
        for (int j = 0; j < 4; j++) {
            dst[j] = mkf4(x[4 * j] + o[4 * j], x[4 * j + 1] + o[4 * j + 1],
                          x[4 * j + 2] + o[4 * j + 2], x[4 * j + 3] + o[4 * j + 3]);
        }
    }
}

// ---------------------------------------------------------------------------
// K4 v3: G1[b,:,:] = A_dyn @ flow[b]. Block = (b, 128-n tile); flow[b] staged
// in LDS (14.7 KB, broadcast reads); AdT read coalesced as float2 (rows padded
// to 308). No atomics: each block owns its outputs.
// ---------------------------------------------------------------------------
__global__ __launch_bounds__(256) void g1_kernel(const float* __restrict__ flow,
                                                 const float* __restrict__ AdT,
                                                 float* __restrict__ G1) {
    __shared__ float sflow[NN * LL];   // 3684 floats
    int b = blockIdx.x, nt = blockIdx.y, t = threadIdx.x;
    const float* fb = flow + (size_t)b * (NN * LL);
    for (int e = t; e < NN * LL; e += 256) sflow[e] = fb[e];
    __syncthreads();

    int lane = t & 63, lq = t >> 6;
    int n = nt * 128 + 2 * lane;
    int l0 = lq * 3;
    float a00 = 0.f, a01 = 0.f, a02 = 0.f, a10 = 0.f, a11 = 0.f, a12 = 0.f;
#pragma unroll 4
    for (int m = 0; m < NN; m++) {
        float2 w = reinterpret_cast<const float2*>(AdT + (size_t)m * ADTS + nt * 128)[lane];
        float f0 = sflow[m * LL + l0];
        float f1 = sflow[m * LL + l0 + 1];
        float f2 = sflow[m * LL + l0 + 2];
        a00 += w.x * f0; a01 += w.x * f1; a02 += w.x * f2;
        a10 += w.y * f0; a11 += w.y * f1; a12 += w.y * f2;
    }
    if (n < NN) {
        float* dst = G1 + ((size_t)b * NN + n) * LL + l0;
        dst[0] = a00; dst[1] = a01; dst[2] = a02;
    }
    if (n + 1 < NN) {
        float* dst = G1 + ((size_t)b * NN + n + 1) * LL + l0;
        dst[0] = a10; dst[1] = a11; dst[2] = a12;
    }
}

// ---------------------------------------------------------------------------
// K5 v3: fused graph-mix + per-vertex MLP. Block = (n, 4 batches); all
// per-n weights + Wt/Wg staged in LDS once. Wave w handles b = 4*blockIdx.y+w.
// ---------------------------------------------------------------------------
__global__ __launch_bounds__(256) void final_kernel(
    const float* __restrict__ xtcn, const float* __restrict__ G1,
    const float* __restrict__ Wg, const float* __restrict__ Wt,
    const float* __restrict__ bg, const float* __restrict__ W1,
    const float* __restrict__ b1, const float* __restrict__ W2,
    const float* __restrict__ b2, const int* __restrict__ ncnt,
    const int* __restrict__ nidx, const float* __restrict__ nw,
    float* __restrict__ out) {
    __shared__ __align__(16) float sWt[512];
    __shared__ __align__(16) float sW1[256];
    __shared__ __align__(16) float sWg[32];
    __shared__ __align__(16) float sBg[32];
    __shared__ float sB1[8], sW2[8];
    __shared__ __align__(16) float sY[4][192];
    __shared__ __align__(16) float4 sHID[4][96];
    __shared__ float sH1[4][96];

    int t = threadIdx.x;
    int n = blockIdx.x;
    int w = t >> 6, t64 = t & 63;
    int b = blockIdx.y * 4 + w;

    // stage weights
    sW1[t] = W1[n * 256 + t];
    sWt[t] = Wt[t];
    sWt[t + 256] = Wt[t + 256];
    if (t < 32) sWg[t] = Wg[t];
    else if (t < 64) sBg[t - 32] = bg[t - 32];
    else if (t < 72) sB1[t - 64] = b1[n * 8 + (t - 64)];
    else if (t < 80) sW2[t - 72] = W2[n * 8 + (t - 72)];
    float b2v = b2[n];
    int cnt = ncnt[n];
    __syncthreads();

    // sparse gather: y = sum_nbr w * xtcn[b, m, :]
    float y0 = 0.f, y1 = 0.f, y2 = 0.f;
    const float* base = xtcn + (size_t)b * NN * 192;
    int i = 0;
    for (; i + 1 < cnt; i += 2) {
        int ma = nidx[n * NBRCAP + i], mb = nidx[n * NBRCAP + i + 1];
        float wa = nw[n * NBRCAP + i], wb = nw[n * NBRCAP + i + 1];
        const float* sa = base + ma * 192;
        const float* sb = base + mb * 192;
        float p0 = sa[t64], p1 = sa[t64 + 64], p2 = sa[t64 + 128];
        float q0 = sb[t64], q1 = sb[t64 + 64], q2 = sb[t64 + 128];
        y0 += wa * p0 + wb * q0; y1 += wa * p1 + wb * q1; y2 += wa * p2 + wb * q2;
    }
    if (i < cnt) {
        int ma = nidx[n * NBRCAP + i];
        float wa = nw[n * NBRCAP + i];
        const float* sa = base + ma * 192;
        y0 += wa * sa[t64]; y1 += wa * sa[t64 + 64]; y2 += wa * sa[t64 + 128];
    }
    sY[w][t64] = y0; sY[w][t64 + 64] = y1; sY[w][t64 + 128] = y2;
    __syncthreads();

    // hid = relu(G1*Wg + y@Wt + bg)  -> sHID[w][96] float4 chunks
#pragma unroll
    for (int p = 0; p < 2; p++) {
        int c = t64 + p * 64;
        if (c < 96) {
            int l = c >> 3, j = c & 7;
            float g = G1[((size_t)b * NN + n) * LL + l];
            float4 wg = reinterpret_cast<const float4*>(sWg)[j];
            float4 acc = reinterpret_cast<const float4*>(sBg)[j];
            acc.x += g * wg.x; acc.y += g * wg.y; acc.z += g * wg.z; acc.w += g * wg.w;
            const float4* yr = reinterpret_cast<const float4*>(&sY[w][l * 16]);
            float4 v0 = yr[0], v1 = yr[1], v2 = yr[2], v3 = yr[3];
            float ye[16] = {v0.x, v0.y, v0.z, v0.w, v1.x, v1.y, v1.z, v1.w,
                            v2.x, v2.y, v2.z, v2.w, v3.x, v3.y, v3.z, v3.w};
#pragma unroll
            for (int d = 0; d < 16; d++) {
                float4 wt = reinterpret_cast<const float4*>(sWt)[d * 8 + j];
                acc.x += ye[d] * wt.x; acc.y += ye[d] * wt.y;
                acc.z += ye[d] * wt.z; acc.w += ye[d] * wt.w;
            }
            acc.x = fmaxf(acc.x, 0.f); acc.y = fmaxf(acc.y, 0.f);
            acc.z = fmaxf(acc.z, 0.f); acc.w = fmaxf(acc.w, 0.f);
            sHID[w][c] = acc;
        }
    }
    __syncthreads();

    // h1 = relu(hid @ W1[n] + b1[n])
#pragma unroll
    for (int p = 0; p < 2; p++) {
        int o = t64 + p * 64;
        if (o < 96) {
            int l = o >> 3, oo = o & 7;
            float acc = sB1[oo];
            float he[32];
#pragma unroll
            for (int k = 0; k < 8; k++) {
                float4 hv = sHID[w][l * 8 + k];
                he[4 * k + 0] = hv.x; he[4 * k + 1] = hv.y;
                he[4 * k + 2] = hv.z; he[4 * k + 3] = hv.w;
            }
#pragma unroll
            for (int c = 0; c < 32; c++) acc += he[c] * sW1[c * 8 + oo];
            sH1[w][o] = fmaxf(acc, 0.f);
        }
    }
    __syncthreads();

    // out = h1 @ W2[n] + b2[n]
    if (t64 < LL) {
        float acc = b2v;
#pragma unroll
        for (int o = 0; o < 8; o++) acc += sH1[w][t64 * 8 + o] * sW2[o];
        out[((size_t)b * NN + n) * LL + t64] = acc;
    }
}

// ---------------------------------------------------------------------------
extern "C" void kernel_launch(void* const* d_in, const int* in_sizes, int n_in,
                              void* d_out, int out_size, void* d_ws, size_t ws_size,
                              hipStream_t stream) {
    const float* flow = (const float*)d_in[0];
    const int* dayc   = (const int*)d_in[1];
    const int* weekc  = (const int*)d_in[2];
    const float* adj  = (const float*)d_in[3];
    const float* demb = (const float*)d_in[4];
    const float* wemb = (const float*)d_in[5];
    const float* Wq = (const float*)d_in[6];  const float* bq = (const float*)d_in[7];
    const float* Wk = (const float*)d_in[8];  const float* bk = (const float*)d_in[9];
    const float* Wv = (const float*)d_in[10]; const float* bv = (const float*)d_in[11];
    const float* Wo = (const float*)d_in[12]; const float* bo = (const float*)d_in[13];
    const float* Wg = (const float*)d_in[14]; const float* Wt = (const float*)d_in[15];
    const float* bg = (const float*)d_in[16];
    const float* W1 = (const float*)d_in[17]; const float* b1 = (const float*)d_in[18];
    const float* W2 = (const float*)d_in[19]; const float* b2 = (const float*)d_in[20];
    float* out = (float*)d_out;
    float* ws  = (float*)d_ws;

    float* xtcn = ws + OFF_XTCN;
    float* G1   = ws + OFF_G1;
    float* AdT  = ws + OFF_ADT;
    float* TE   = ws + OFF_TE;
    float* his  = ws + OFF_HIS;
    float* nw   = ws + OFF_NW;
    int*   nidx = (int*)(ws + OFF_NIDX);
    int*   ncnt = (int*)(ws + OFF_NCNT);

    his_kernel<<<(NN * HISW + 255) / 256, 256, 0, stream>>>(flow, his);
    te_kernel<<<(NB * LL * DDIM + 255) / 256, 256, 0, stream>>>(dayc, weekc, demb, wemb, TE);
    adyn_kernel<<<NN, 256, 0, stream>>>(his, AdT);
    nbr_kernel<<<NN, 64, 0, stream>>>(adj, ncnt, nidx, nw);
    attn_kernel<<<(NBN + AGRP - 1) / AGRP, 256, 0, stream>>>(flow, TE, Wq, bq, Wk, bk,
                                                             Wv, bv, Wo, bo, xtcn);
    g1_kernel<<<dim3(NB, 3), 256, 0, stream>>>(flow, AdT, G1);
    final_kernel<<<dim3(NN, 64), 256, 0, stream>>>(xtcn, G1, Wg, Wt, bg, W1, b1, W2, b2,
                                                   ncnt, nidx, nw, out);
}